// Round 6
// baseline (494.790 us; speedup 1.0000x reference)
//
#include <hip/hip_runtime.h>
#include <hip/hip_cooperative_groups.h>
#include <math.h>

namespace cg = cooperative_groups;

// DigitCaps dynamic routing, fused single cooperative kernel.
// - u recomputed per pass (never materialized); logits linear in v => no logit buf.
// - W/x read DIRECTLY from global (wave-uniform dwordx4 broadcast for W,
//   coalesced lane dwordx4 for x). No LDS staging: each slab belongs to one
//   block, each W address to one wave -- LDS pipe freed (R5 bottleneck).
// - LDS only for softmax exchange; 1 barrier/iter (parity dbuf, self-summed denom).
// - conv + 3 passes + 3 reduce/squash phases chained with grid.sync() in ONE
//   launch (R5 spent ~82us on 8 small-kernel launches). Fallback to discrete
//   launches if cooperative launch is unavailable.

namespace {
constexpr int B_   = 128;
constexpr int N_   = 4608;
constexpr int C_   = 10;
constexpr int L_   = 16;
constexpr int BCL  = B_ * C_ * L_;   // 20480
constexpr int NB   = 256;            // blocks == CUs (cooperative co-residency)
constexpr int NT   = 640;            // 10 waves: one per output capsule
constexpr int GT   = NB * NT;        // 163840 grid threads
constexpr int TILE = N_ / NB;        // 18 n per block
}

typedef _Float16 h2 __attribute__((ext_vector_type(2)));
union U32H2 { unsigned int u; h2 h; };
__device__ inline h2 uph(unsigned int v) { U32H2 t; t.u = v; return t.h; }
__device__ inline unsigned int packh2(float a, float b) {
    h2 h; h[0] = (_Float16)a; h[1] = (_Float16)b;
    U32H2 t; t.h = h; return t.u;
}

#if defined(__has_builtin)
#if __has_builtin(__builtin_amdgcn_fdot2)
#define HAVE_FDOT2 1
#endif
#endif
__device__ inline float fdot2(h2 a, h2 b, float c) {
#ifdef HAVE_FDOT2
    return __builtin_amdgcn_fdot2(a, b, c, false);
#else
    return c + (float)a[0] * (float)b[0] + (float)a[1] * (float)b[1];
#endif
}

// ---- phase: convert W -> packed half2 [N][jp=4][160], x -> [N][B] uint4 ----
__device__ __forceinline__ void conv_phase(const float* __restrict__ x,
                                           const float* __restrict__ W,
                                           unsigned int* __restrict__ Wh,
                                           unsigned int* __restrict__ Xh) {
    const int g = blockIdx.x * NT + threadIdx.x;
    for (int i = g; i < N_ * 640; i += GT) {          // 18 iters exactly
        const int cl = i % 160;
        const int r  = i / 160;
        const int n  = r >> 2, jp = r & 3;
        const float* p = W + ((size_t)n * 8 + jp * 2) * 160 + cl;
        Wh[i] = packh2(p[0], p[160]);
    }
    for (int i = g; i < N_ * B_; i += GT) {           // coalesced reads (i = b*N+n)
        const int n = i % N_;
        const int b = i / N_;
        const float4 f0 = *(const float4*)(x + (size_t)i * 8);
        const float4 f1 = *(const float4*)(x + (size_t)i * 8 + 4);
        uint4 o;
        o.x = packh2(f0.x, f0.y); o.y = packh2(f0.z, f0.w);
        o.z = packh2(f1.x, f1.y); o.w = packh2(f1.z, f1.w);
        ((uint4*)Xh)[(size_t)n * B_ + b] = o;         // transpose scatter, L2-merged
    }
}

// ---- phase: one routing pass. MODE0 uniform; MODE1 t=u.v0; MODE2 t=u.(v0+v1) ----
template<int MODE>
__device__ __forceinline__ void pass_phase(
    const unsigned int* __restrict__ Xh,   // [N][B] uint4 (packed f16 x)
    const unsigned int* __restrict__ Wh,   // [N][4][160] half2
    const float* __restrict__ va, const float* __restrict__ vb,
    float* __restrict__ partials,          // [NB][B][C][L]
    float* sm)                             // 2*C_*128 floats (softmax exchange)
{
    const int tid = threadIdx.x;
    const int c   = tid >> 6;
    const int bl  = tid & 63;
    const int n0  = blockIdx.x * TILE;

    float vr0[L_], vr1[L_];
    if (MODE >= 1) {
        #pragma unroll
        for (int l = 0; l < L_; ++l) {
            vr0[l] = va[((size_t)bl * C_ + c) * L_ + l];
            vr1[l] = va[((size_t)(bl + 64) * C_ + c) * L_ + l];
        }
        if (MODE == 2) {
            #pragma unroll
            for (int l = 0; l < L_; ++l) {
                vr0[l] += vb[((size_t)bl * C_ + c) * L_ + l];
                vr1[l] += vb[((size_t)(bl + 64) * C_ + c) * L_ + l];
            }
        }
    }

    float s0[L_], s1[L_];
    #pragma unroll
    for (int l = 0; l < L_; ++l) { s0[l] = 0.f; s1[l] = 0.f; }

    #pragma unroll 2
    for (int nn = 0; nn < TILE; ++nn) {
        const int n = n0 + nn;
        // x: coalesced lane dwordx4 from global (slab private to this block, L1-hot)
        const uint4 xq0 = ((const uint4*)Xh)[(size_t)n * B_ + bl];
        const uint4 xq1 = ((const uint4*)Xh)[(size_t)n * B_ + 64 + bl];
        const unsigned int xa0[4] = {xq0.x, xq0.y, xq0.z, xq0.w};
        const unsigned int xa1[4] = {xq1.x, xq1.y, xq1.z, xq1.w};
        // W: wave-uniform global dwordx4 (one transaction + broadcast; address is
        // threadIdx-derived so it stays VMEM, not s_load)
        const unsigned int* wb = Wh + (size_t)n * 640 + c * 16;

        float u0[L_], u1[L_];
        #pragma unroll
        for (int l = 0; l < L_; ++l) { u0[l] = 0.f; u1[l] = 0.f; }
        #pragma unroll
        for (int jp = 0; jp < 4; ++jp) {
            const h2 xh0 = uph(xa0[jp]);
            const h2 xh1 = uph(xa1[jp]);
            #pragma unroll
            for (int q = 0; q < 4; ++q) {
                const uint4 w4 = *(const uint4*)(wb + jp * 160 + q * 4);
                const unsigned int wa[4] = {w4.x, w4.y, w4.z, w4.w};
                #pragma unroll
                for (int e = 0; e < 4; ++e) {
                    const h2 wh = uph(wa[e]);
                    u0[4 * q + e] = fdot2(xh0, wh, u0[4 * q + e]);
                    u1[4 * q + e] = fdot2(xh1, wh, u1[4 * q + e]);
                }
            }
        }

        if (MODE == 0) {
            #pragma unroll
            for (int l = 0; l < L_; ++l) { s0[l] += u0[l]; s1[l] += u1[l]; }
        } else {
            float ta0 = 0.f, tb0 = 0.f, ta1 = 0.f, tb1 = 0.f;   // 2-acc: half chain depth
            #pragma unroll
            for (int l = 0; l < L_; l += 2) {
                ta0 = fmaf(u0[l], vr0[l], ta0);  tb0 = fmaf(u0[l+1], vr0[l+1], tb0);
                ta1 = fmaf(u1[l], vr1[l], ta1);  tb1 = fmaf(u1[l+1], vr1[l+1], tb1);
            }
            const float e0 = __expf(ta0 + tb0);   // |t| small: no max-shift needed
            const float e1 = __expf(ta1 + tb1);
            const int p = nn & 1;                 // parity dbuf -> 1 barrier/iter
            sm[(p * C_ + c) * 128 + bl]      = e0;
            sm[(p * C_ + c) * 128 + 64 + bl] = e1;
            __syncthreads();
            float es0 = 0.f, es1 = 0.f;
            #pragma unroll
            for (int cc = 0; cc < C_; ++cc) {     // self-summed denom, conflict-free
                es0 += sm[(p * C_ + cc) * 128 + bl];
                es1 += sm[(p * C_ + cc) * 128 + 64 + bl];
            }
            const float w0 = e0 * __builtin_amdgcn_rcpf(es0);
            const float w1 = e1 * __builtin_amdgcn_rcpf(es1);
            #pragma unroll
            for (int l = 0; l < L_; ++l) {
                s0[l] = fmaf(w0, u0[l], s0[l]);
                s1[l] = fmaf(w1, u1[l], s1[l]);
            }
        }
    }

    float* p0 = partials + (((size_t)blockIdx.x * B_ + bl) * C_ + c) * L_;
    float* p1 = partials + (((size_t)blockIdx.x * B_ + bl + 64) * C_ + c) * L_;
    #pragma unroll
    for (int q = 0; q < 4; ++q) {
        *(float4*)(p0 + 4 * q) = make_float4(s0[4*q], s0[4*q+1], s0[4*q+2], s0[4*q+3]);
        *(float4*)(p1 + 4 * q) = make_float4(s1[4*q], s1[4*q+1], s1[4*q+2], s1[4*q+3]);
    }
}

// ---- phase: sum NB chunks, bias, squash. 5 active waves/block, 1 wave per (b,c). ----
__device__ __forceinline__ void reduce_phase(const float* __restrict__ partials,
                                             const float* __restrict__ biases,
                                             float* __restrict__ vout, float scale)
{
    const int wv = threadIdx.x >> 6;
    if (wv < 5) {                              // no early return: grid.sync follows
        const int w    = blockIdx.x * 5 + wv;  // (b*C+c): 0..1279
        const int lane = threadIdx.x & 63;
        const int l = lane & 15, grp = lane >> 4;
        const int idx = w * L_ + l;
        const float* base = partials + (size_t)grp * (NB / 4) * BCL + idx;
        float a0 = 0.f, a1 = 0.f, a2 = 0.f, a3 = 0.f;
        #pragma unroll
        for (int k = 0; k < NB / 4; k += 4) {  // 64 chunks per grp, ILP-4
            a0 += base[(size_t)(k + 0) * BCL];
            a1 += base[(size_t)(k + 1) * BCL];
            a2 += base[(size_t)(k + 2) * BCL];
            a3 += base[(size_t)(k + 3) * BCL];
        }
        float a = (a0 + a1) + (a2 + a3);
        a += __shfl_xor(a, 16);
        a += __shfl_xor(a, 32);
        const float s = a * scale + biases[(w % C_) * L_ + l];
        float n2 = s * s;
        #pragma unroll
        for (int o = 8; o; o >>= 1) n2 += __shfl_xor(n2, o);
        const float nrm = sqrtf(n2);
        const float f = n2 / ((1.f + n2) * (nrm + 1e-7f));
        if (grp == 0) vout[idx] = f * s;
    }
}

// ---- the fused cooperative kernel ----
__global__ void __launch_bounds__(NT, 3) digitcaps_fused(
    const float* __restrict__ x, const float* __restrict__ W,
    const float* __restrict__ biases,
    unsigned int* __restrict__ Wh, unsigned int* __restrict__ Xh,
    float* __restrict__ partials, float* __restrict__ v0, float* __restrict__ v1,
    float* __restrict__ out)
{
    cg::grid_group grid = cg::this_grid();
    __shared__ float sm[2 * C_ * 128];

    conv_phase(x, W, Wh, Xh);
    grid.sync();
    pass_phase<0>(Xh, Wh, nullptr, nullptr, partials, sm);
    grid.sync();
    reduce_phase(partials, biases, v0, 0.1f);
    grid.sync();
    pass_phase<1>(Xh, Wh, v0, nullptr, partials, sm);
    grid.sync();
    reduce_phase(partials, biases, v1, 1.0f);
    grid.sync();
    pass_phase<2>(Xh, Wh, v0, v1, partials, sm);
    grid.sync();
    reduce_phase(partials, biases, out, 1.0f);
}

// ---- fallback discrete kernels (same phases) if cooperative launch fails ----
__global__ void __launch_bounds__(NT, 3) k_conv(const float* __restrict__ x,
                                                const float* __restrict__ W,
                                                unsigned int* __restrict__ Wh,
                                                unsigned int* __restrict__ Xh) {
    conv_phase(x, W, Wh, Xh);
}
template<int MODE>
__global__ void __launch_bounds__(NT, 3) k_pass(const unsigned int* __restrict__ Xh,
                                                const unsigned int* __restrict__ Wh,
                                                const float* __restrict__ va,
                                                const float* __restrict__ vb,
                                                float* __restrict__ partials) {
    __shared__ float sm[2 * C_ * 128];
    pass_phase<MODE>(Xh, Wh, va, vb, partials, sm);
}
__global__ void __launch_bounds__(NT, 3) k_reduce(const float* __restrict__ partials,
                                                  const float* __restrict__ biases,
                                                  float* __restrict__ vout, float scale) {
    reduce_phase(partials, biases, vout, scale);
}

extern "C" void kernel_launch(void* const* d_in, const int* in_sizes, int n_in,
                              void* d_out, int out_size, void* d_ws, size_t ws_size,
                              hipStream_t stream) {
    const float* x      = (const float*)d_in[0];
    const float* W      = (const float*)d_in[1];
    const float* biases = (const float*)d_in[2];
    float* out = (float*)d_out;

    unsigned int* Wh = (unsigned int*)d_ws;               // N*640 u32 = 11.8 MB
    unsigned int* Xh = Wh + (size_t)N_ * 640;             // N*512 u32 =  9.4 MB
    float* partials  = (float*)(Xh + (size_t)N_ * 512);   // NB*BCL    = 21.0 MB
    float* v0        = partials + (size_t)NB * BCL;
    float* v1        = v0 + BCL;

    void* args[] = { (void*)&x, (void*)&W, (void*)&biases, (void*)&Wh, (void*)&Xh,
                     (void*)&partials, (void*)&v0, (void*)&v1, (void*)&out };
    hipError_t err = hipLaunchCooperativeKernel((const void*)digitcaps_fused,
                                                dim3(NB), dim3(NT), args, 0, stream);
    if (err != hipSuccess) {
        // deterministic fallback: identical phases as discrete launches
        const dim3 g(NB), b(NT);
        k_conv<<<g, b, 0, stream>>>(x, W, Wh, Xh);
        k_pass<0><<<g, b, 0, stream>>>(Xh, Wh, nullptr, nullptr, partials);
        k_reduce<<<g, b, 0, stream>>>(partials, biases, v0, 0.1f);
        k_pass<1><<<g, b, 0, stream>>>(Xh, Wh, v0, nullptr, partials);
        k_reduce<<<g, b, 0, stream>>>(partials, biases, v1, 1.0f);
        k_pass<2><<<g, b, 0, stream>>>(Xh, Wh, v0, v1, partials);
        k_reduce<<<g, b, 0, stream>>>(partials, biases, out, 1.0f);
    }
}

// Round 7
// 361.963 us; speedup vs baseline: 1.3670x; 1.3670x over previous
//
#include <hip/hip_runtime.h>
#include <math.h>

// DigitCaps dynamic routing, fp32-accum f16-dot2, u never materialized,
// logits linear in v (b2 = u.(v0+v1)) => no logit buffer.
// R7: back to discrete launches (R6 cooperative fused = spills + 1 block/CU).
//  - 1 batch/lane (R3 shape): ~60 live VGPRs, no spill, 2-3 blocks/CU.
//  - W/x read DIRECT from global (packed f16): wave-uniform dwordx4 W broadcast
//    rides the deep VMEM queue instead of the serializing LDS/lgkm path that
//    capped R3/R5 at ~50 us/pass. No staging barriers. LDS = softmax only.
//  - 7 launches total (conv merged; reduce_a+b merged).

namespace {
constexpr int B_   = 128;
constexpr int N_   = 4608;
constexpr int C_   = 10;
constexpr int L_   = 16;
constexpr int BCL  = B_ * C_ * L_;    // 20480
constexpr int NCH  = 384;             // n-chunks; grid = (384, 2 batch halves)
constexpr int TILE = N_ / NCH;        // 12
}

typedef _Float16 h2 __attribute__((ext_vector_type(2)));
union U32H2 { unsigned int u; h2 h; };
__device__ inline h2 uph(unsigned int v) { U32H2 t; t.u = v; return t.h; }
__device__ inline unsigned int packh2(float a, float b) {
    h2 h; h[0] = (_Float16)a; h[1] = (_Float16)b;
    U32H2 t; t.h = h; return t.u;
}

#if defined(__has_builtin)
#if __has_builtin(__builtin_amdgcn_fdot2)
#define HAVE_FDOT2 1
#endif
#endif
__device__ inline float fdot2(h2 a, h2 b, float c) {
#ifdef HAVE_FDOT2
    return __builtin_amdgcn_fdot2(a, b, c, false);
#else
    return c + (float)a[0] * (float)b[0] + (float)a[1] * (float)b[1];
#endif
}

// Merged conversion: W[N][8][160]f32 -> Wh[N][4][160] half2 ;
//                    x[B][N][8]f32  -> Xh[N][128] uint4 (transposed, packed)
__global__ __launch_bounds__(256)
void conv_wx(const float* __restrict__ x, const float* __restrict__ W,
             unsigned int* __restrict__ Wh, unsigned int* __restrict__ Xh) {
    const int g  = blockIdx.x * 256 + threadIdx.x;
    const int GT = gridDim.x * 256;
    for (int i = g; i < N_ * 640; i += GT) {
        const int cl = i % 160;
        const int r  = i / 160;
        const int n  = r >> 2, jp = r & 3;
        const float* p = W + ((size_t)n * 8 + jp * 2) * 160 + cl;
        Wh[i] = packh2(p[0], p[160]);
    }
    for (int i = g; i < N_ * B_; i += GT) {      // i = b*N + n (coalesced reads)
        const int n = i % N_;
        const int b = i / N_;
        const float4 f0 = *(const float4*)(x + (size_t)i * 8);
        const float4 f1 = *(const float4*)(x + (size_t)i * 8 + 4);
        uint4 o;
        o.x = packh2(f0.x, f0.y); o.y = packh2(f0.z, f0.w);
        o.z = packh2(f1.x, f1.y); o.w = packh2(f1.z, f1.w);
        ((uint4*)Xh)[(size_t)n * B_ + b] = o;
    }
}

// MODE 0: iter0 uniform coupling (1/10 folded into reduce scale)
// MODE 1: logits t = u.v0      MODE 2: logits t = u.(v0+v1)
// Block: 640 thr = 10 waves (one per capsule c), 64 batches (blockIdx.y half).
template<int MODE>
__global__ __launch_bounds__(640, 6)
void pass_kernel(const unsigned int* __restrict__ Xh,   // [N][128] uint4 (f16 x)
                 const unsigned int* __restrict__ Wh,   // [N][4][160] half2
                 const float* __restrict__ va,
                 const float* __restrict__ vb,
                 float* __restrict__ partials)          // [NCH][B][C][L]
{
    __shared__ float sm[2][C_][64];      // exp(t) exchange, parity double-buffered

    const int tid = threadIdx.x;
    const int c   = tid >> 6;
    const int bl  = tid & 63;
    const int bg  = blockIdx.y * 64 + bl;
    const int n0  = blockIdx.x * TILE;

    float vr[L_];
    if (MODE >= 1) {
        const float4* pa = (const float4*)(va + ((size_t)bg * C_ + c) * L_);
        #pragma unroll
        for (int q = 0; q < 4; ++q) {
            const float4 f = pa[q];
            vr[4*q] = f.x; vr[4*q+1] = f.y; vr[4*q+2] = f.z; vr[4*q+3] = f.w;
        }
        if (MODE == 2) {
            const float4* pb = (const float4*)(vb + ((size_t)bg * C_ + c) * L_);
            #pragma unroll
            for (int q = 0; q < 4; ++q) {
                const float4 f = pb[q];
                vr[4*q] += f.x; vr[4*q+1] += f.y; vr[4*q+2] += f.z; vr[4*q+3] += f.w;
            }
        }
    }

    float s[L_];
    #pragma unroll
    for (int l = 0; l < L_; ++l) s[l] = 0.f;

    // x prefetch for software pipelining (decouple load->use across iterations)
    uint4 xq = ((const uint4*)Xh)[(size_t)n0 * B_ + blockIdx.y * 64 + bl];

    for (int nn = 0; nn < TILE; ++nn) {
        const int n = n0 + nn;
        const unsigned int xa[4] = {xq.x, xq.y, xq.z, xq.w};
        if (nn + 1 < TILE)
            xq = ((const uint4*)Xh)[(size_t)(n + 1) * B_ + blockIdx.y * 64 + bl];

        // W: wave-uniform global dwordx4 (1 transaction + broadcast, L1/L2-hot)
        const unsigned int* wb = Wh + (size_t)n * 640 + c * 16;

        float u[L_];
        #pragma unroll
        for (int l = 0; l < L_; ++l) u[l] = 0.f;
        #pragma unroll
        for (int jp = 0; jp < 4; ++jp) {
            const h2 xh = uph(xa[jp]);
            #pragma unroll
            for (int q = 0; q < 4; ++q) {
                const uint4 w4 = *(const uint4*)(wb + jp * 160 + q * 4);
                const unsigned int wa[4] = {w4.x, w4.y, w4.z, w4.w};
                #pragma unroll
                for (int e = 0; e < 4; ++e)
                    u[4 * q + e] = fdot2(uph(wa[e]), xh, u[4 * q + e]);
            }
        }

        if (MODE == 0) {
            #pragma unroll
            for (int l = 0; l < L_; ++l) s[l] += u[l];
        } else {
            float ta = 0.f, tb = 0.f;
            #pragma unroll
            for (int l = 0; l < L_; l += 2) {
                ta = fmaf(u[l],     vr[l],     ta);
                tb = fmaf(u[l + 1], vr[l + 1], tb);
            }
            const float e = __expf(ta + tb);     // |t| small: no max-shift needed
            const int p = nn & 1;                // parity dbuf -> 1 barrier/iter
            sm[p][c][bl] = e;
            __syncthreads();
            float es = 0.f;
            #pragma unroll
            for (int cc = 0; cc < C_; ++cc) es += sm[p][cc][bl];
            const float w = e * __builtin_amdgcn_rcpf(es);
            #pragma unroll
            for (int l = 0; l < L_; ++l) s[l] = fmaf(w, u[l], s[l]);
        }
    }

    float* p = partials + (((size_t)blockIdx.x * B_ + bg) * C_ + c) * L_;
    #pragma unroll
    for (int q = 0; q < 4; ++q)
        *(float4*)(p + 4 * q) = make_float4(s[4*q], s[4*q+1], s[4*q+2], s[4*q+3]);
}

// Merged reduce: sum NCH chunks, bias, squash. 160 blocks x 128 thr, coalesced.
__global__ __launch_bounds__(128)
void reduce_squash(const float* __restrict__ partials,
                   const float* __restrict__ biases,
                   float* __restrict__ vout, float scale)
{
    const int idx = blockIdx.x * 128 + threadIdx.x;   // (b*C+c)*16+l, < BCL
    const float* base = partials + idx;
    float a0 = 0.f, a1 = 0.f, a2 = 0.f, a3 = 0.f;
    #pragma unroll 4
    for (int k = 0; k < NCH; k += 4) {
        a0 += base[(size_t)(k + 0) * BCL];
        a1 += base[(size_t)(k + 1) * BCL];
        a2 += base[(size_t)(k + 2) * BCL];
        a3 += base[(size_t)(k + 3) * BCL];
    }
    const float s = ((a0 + a1) + (a2 + a3)) * scale + biases[idx % 160];
    float n2 = s * s;
    #pragma unroll
    for (int o = 8; o; o >>= 1) n2 += __shfl_xor(n2, o, 16);
    const float n = sqrtf(n2);
    const float f = n2 / ((1.f + n2) * (n + 1e-7f));
    vout[idx] = f * s;
}

extern "C" void kernel_launch(void* const* d_in, const int* in_sizes, int n_in,
                              void* d_out, int out_size, void* d_ws, size_t ws_size,
                              hipStream_t stream) {
    const float* x      = (const float*)d_in[0];
    const float* W      = (const float*)d_in[1];
    const float* biases = (const float*)d_in[2];
    float* out = (float*)d_out;

    unsigned int* Wh = (unsigned int*)d_ws;               // N*640 u32 = 11.8 MB
    unsigned int* Xh = Wh + (size_t)N_ * 640;             // N*512 u32 =  9.4 MB
    float* partials  = (float*)(Xh + (size_t)N_ * 512);   // 384*20480 = 31.5 MB
    float* v0        = partials + (size_t)NCH * BCL;
    float* v1        = v0 + BCL;

    const dim3 pg(NCH, 2), pb(640);
    const dim3 rg(BCL / 128), rb(128);

    conv_wx<<<1024, 256, 0, stream>>>(x, W, Wh, Xh);

    pass_kernel<0><<<pg, pb, 0, stream>>>(Xh, Wh, nullptr, nullptr, partials);
    reduce_squash<<<rg, rb, 0, stream>>>(partials, biases, v0, 0.1f);

    pass_kernel<1><<<pg, pb, 0, stream>>>(Xh, Wh, v0, nullptr, partials);
    reduce_squash<<<rg, rb, 0, stream>>>(partials, biases, v1, 1.0f);

    pass_kernel<2><<<pg, pb, 0, stream>>>(Xh, Wh, v0, v1, partials);
    reduce_squash<<<rg, rb, 0, stream>>>(partials, biases, out, 1.0f);
}